// Round 1
// baseline (51758.765 us; speedup 1.0000x reference)
//
#include <hip/hip_runtime.h>
#include <hip/hip_bf16.h>

// ---------- types ----------
typedef __bf16 v8bf __attribute__((ext_vector_type(8)));
typedef float  v4f  __attribute__((ext_vector_type(4)));

__device__ inline const __attribute__((address_space(1))) void* gcast(const void* p) {
    return (const __attribute__((address_space(1))) void*)p;
}
__device__ inline __attribute__((address_space(3))) void* scast(void* p) {
    return (__attribute__((address_space(3))) void*)p;
}

__device__ inline float fast_tanh(float x) {
    // tanh(x) = 1 - 2/(exp(2x)+1); __expf handles +/-inf limits correctly
    float e = __expf(2.0f * x);
    return 1.0f - 2.0f / (e + 1.0f);
}

// ---------- setup kernel 1: SE = z @ dec_W + dec_b  (128 x 2048) ----------
__global__ __launch_bounds__(256) void se_kernel(const float* __restrict__ z,
                                                 const float* __restrict__ decW,
                                                 const float* __restrict__ decb,
                                                 float* __restrict__ SE) {
    __shared__ float zs[128];
    const int b = blockIdx.x, t = threadIdx.x;
    if (t < 128) zs[t] = z[b * 128 + t];
    __syncthreads();
    for (int c = t; c < 2048; c += 256) {
        float acc = decb[c];
        #pragma unroll 4
        for (int k = 0; k < 128; ++k) acc += zs[k] * decW[k * 2048 + c];
        SE[b * 2048 + c] = acc;
    }
}

// ---------- setup kernel 2: deformation + aliveness + y0 assembly ----------
// block r = (b, s); writes y0 (fp32 state), ybf (bf16), traj[0]
__global__ __launch_bounds__(128) void init_kernel(
    const float* __restrict__ SE, const float* __restrict__ tmpl,
    const float* __restrict__ dW1, const float* __restrict__ db1,
    const float* __restrict__ dW2, const float* __restrict__ db2,
    const float* __restrict__ aW1, const float* __restrict__ ab1,
    const float* __restrict__ aW2, const float* __restrict__ ab2,
    float* __restrict__ y, __bf16* __restrict__ ybf, float* __restrict__ out0) {
    __shared__ float se[64];
    __shared__ float h[128];
    __shared__ float ah[32];
    __shared__ float alive;
    const int r = blockIdx.x, b = r >> 5, s = r & 31, t = threadIdx.x;
    if (t < 64) se[t] = SE[b * 2048 + s * 64 + t];
    __syncthreads();
    {   // h = relu(se @ def_W1 + def_b1), 128 wide
        float acc = db1[t];
        #pragma unroll 4
        for (int k = 0; k < 64; ++k) acc += se[k] * dW1[k * 128 + t];
        h[t] = fmaxf(acc, 0.0f);
    }
    if (t < 32) {  // ah = relu(se @ al_W1 + al_b1)
        float acc = ab1[t];
        #pragma unroll 4
        for (int k = 0; k < 64; ++k) acc += se[k] * aW1[k * 32 + t];
        ah[t] = fmaxf(acc, 0.0f);
    }
    __syncthreads();
    if (t == 0) {
        float lg = ab2[0];
        #pragma unroll
        for (int j = 0; j < 32; ++j) lg += ah[j] * aW2[j];
        alive = 1.0f / (1.0f + __expf(-lg));
    }
    __syncthreads();
    if (t < 99) {
        float acc = db2[t];
        #pragma unroll 4
        for (int j = 0; j < 128; ++j) acc += h[j] * dW2[j * 99 + t];
        float v = (tmpl[s * 99 + t] + acc) * alive;
        int idx = b * 3200 + s * 99 + t;
        y[idx] = v; ybf[idx] = (__bf16)v; out0[idx] = v;
    } else if (t == 99) {
        int idx = b * 3200 + 3168 + s;
        y[idx] = alive; ybf[idx] = (__bf16)alive; out0[idx] = alive;
    }
}

// ---------- transpose fp32 (R x C) -> bf16 (C x R) ----------
__global__ __launch_bounds__(256) void transpose_bf16(const float* __restrict__ W,
                                                      __bf16* __restrict__ WT,
                                                      int R, int C) {
    __shared__ float tile[32][33];
    const int tx = threadIdx.x & 31, ty = threadIdx.x >> 5;
    const int c0 = blockIdx.x * 32, r0 = blockIdx.y * 32;
    #pragma unroll
    for (int i = 0; i < 4; ++i)
        tile[ty + 8 * i][tx] = W[(long)(r0 + ty + 8 * i) * C + c0 + tx];
    __syncthreads();
    #pragma unroll
    for (int i = 0; i < 4; ++i)
        WT[(long)(c0 + ty + 8 * i) * R + r0 + tx] = (__bf16)tile[tx][ty + 8 * i];
}

// ---------- main GEMM: C(128 x N) = A(128 x K, bf16) * BT(N x K, bf16)^T ----------
// BM=32, BN=64, BK=64, 256 threads (4 waves), per-wave 32x16 (2 MFMA acc).
// mode 0: H = tanh(C + bias) -> obf (bf16)                       [phase 1]
// mode 1: k=C+bias; S=k;      ybf=bf16(y + cc*k)                 [eval 1]
// mode 2: k=C+bias; S+=2k;    ybf=bf16(y + cc*k)                 [evals 2,3]
// mode 3: k=C+bias; yn=y+dt6*(S+k); y=yn; ybf=bf16(yn); traj=yn  [eval 4]
__global__ __launch_bounds__(256) void gemm_step(
    const __bf16* __restrict__ A, const __bf16* __restrict__ BT,
    const float* __restrict__ bias, int K, int nTiles, int mode, float cc, float dt6,
    __bf16* __restrict__ obf, float* __restrict__ y, float* __restrict__ S,
    float* __restrict__ traj) {
    // XOR-swizzled chunk layout: chunk(row, c) stored at index row*8 + (c ^ (row&7));
    // staging is contiguous lane*16B -> global_load_lds-compatible; reads are 2-way
    // bank aliased only (free).
    __shared__ __attribute__((aligned(16))) __bf16 lA[32 * 64];
    __shared__ __attribute__((aligned(16))) __bf16 lB[64 * 64];

    const int t = threadIdx.x;
    const int lane = t & 63, w = t >> 6, q = lane >> 4, c16 = lane & 15;
    const int mt = blockIdx.x / nTiles, nt = blockIdx.x % nTiles;
    const int m0 = mt * 32, n0 = nt * 64;
    const int N = nTiles * 64;

    // staging addresses: thread t stages chunk (r = t>>3, cg = (t&7)^(r&7))
    const int ar = t >> 3;
    const int acg = (t & 7) ^ (ar & 7);
    const __bf16* gA  = A  + (long)(m0 + ar) * K + acg * 8;
    const __bf16* gB0 = BT + (long)(n0 + ar) * K + acg * 8;
    const __bf16* gB1 = gB0 + (long)32 * K;

    v4f acc0 = {0.f, 0.f, 0.f, 0.f};
    v4f acc1 = {0.f, 0.f, 0.f, 0.f};

    const int rowA0 = c16, rowA1 = 16 + c16, nloc = 16 * w + c16;
    const int swA = rowA0 & 7;          // same for rowA1
    const int swB = nloc & 7;

    for (int k0 = 0; k0 < K; k0 += 64) {
        __builtin_amdgcn_global_load_lds(gcast(gA  + k0), scast(&lA[t * 8]),        16, 0, 0);
        __builtin_amdgcn_global_load_lds(gcast(gB0 + k0), scast(&lB[t * 8]),        16, 0, 0);
        __builtin_amdgcn_global_load_lds(gcast(gB1 + k0), scast(&lB[2048 + t * 8]), 16, 0, 0);
        __syncthreads();
        #pragma unroll
        for (int kc = 0; kc < 2; ++kc) {
            const int cq = q + 4 * kc;
            v8bf a0 = *(const v8bf*)&lA[(rowA0 * 8 + (cq ^ swA)) * 8];
            v8bf a1 = *(const v8bf*)&lA[(rowA1 * 8 + (cq ^ swA)) * 8];
            v8bf bb = *(const v8bf*)&lB[(nloc  * 8 + (cq ^ swB)) * 8];
            acc0 = __builtin_amdgcn_mfma_f32_16x16x32_bf16(a0, bb, acc0, 0, 0, 0);
            acc1 = __builtin_amdgcn_mfma_f32_16x16x32_bf16(a1, bb, acc1, 0, 0, 0);
        }
        __syncthreads();
    }

    // epilogue: lane holds D[row = 16*mA + 4*q + r][col = 16*w + c16]
    const int gcol = n0 + 16 * w + c16;
    const float b0 = bias[gcol];
    #pragma unroll
    for (int mA = 0; mA < 2; ++mA) {
        v4f acc = mA ? acc1 : acc0;
        #pragma unroll
        for (int r = 0; r < 4; ++r) {
            const int grow = m0 + 16 * mA + 4 * q + r;
            const float v = acc[r] + b0;
            const long idx = (long)grow * N + gcol;
            if (mode == 0) {
                obf[idx] = (__bf16)fast_tanh(v);
            } else if (mode == 1) {
                S[idx] = v;
                obf[idx] = (__bf16)(y[idx] + cc * v);
            } else if (mode == 2) {
                S[idx] += 2.0f * v;
                obf[idx] = (__bf16)(y[idx] + cc * v);
            } else {
                float yn = y[idx] + dt6 * (S[idx] + v);
                y[idx] = yn;
                obf[idx] = (__bf16)yn;
                traj[idx] = yn;
            }
        }
    }
}

// ---------- host ----------
extern "C" void kernel_launch(void* const* d_in, const int* in_sizes, int n_in,
                              void* d_out, int out_size, void* d_ws, size_t ws_size,
                              hipStream_t stream) {
    const float* z     = (const float*)d_in[0];
    const float* decW  = (const float*)d_in[1];
    const float* decb  = (const float*)d_in[2];
    const float* tmpl  = (const float*)d_in[3];
    const float* dW1   = (const float*)d_in[4];
    const float* db1   = (const float*)d_in[5];
    const float* dW2   = (const float*)d_in[6];
    const float* db2   = (const float*)d_in[7];
    const float* aW1   = (const float*)d_in[8];
    const float* ab1   = (const float*)d_in[9];
    const float* aW2   = (const float*)d_in[10];
    const float* ab2   = (const float*)d_in[11];
    const float* odeW1 = (const float*)d_in[12];
    const float* odeb1 = (const float*)d_in[13];
    const float* odeW2 = (const float*)d_in[14];
    const float* odeb2 = (const float*)d_in[15];
    float* out = (float*)d_out;

    char* ws = (char*)d_ws;
    size_t off = 0;
    auto alloc = [&](size_t bytes) -> void* {
        void* p = ws + off;
        off = (off + bytes + 255) & ~(size_t)255;
        return p;
    };
    __bf16* w1t = (__bf16*)alloc((size_t)4096 * 3200 * 2);  // W1^T: (4096 x 3200)
    __bf16* w2t = (__bf16*)alloc((size_t)3200 * 4096 * 2);  // W2^T: (3200 x 4096)
    float*  SE  = (float*)alloc((size_t)128 * 2048 * 4);
    float*  yst = (float*)alloc((size_t)409600 * 4);
    float*  Sac = (float*)alloc((size_t)409600 * 4);
    __bf16* ybf = (__bf16*)alloc((size_t)409600 * 2);
    __bf16* hbf = (__bf16*)alloc((size_t)128 * 4096 * 2);

    // weights -> bf16 transposed
    transpose_bf16<<<dim3(128, 100), 256, 0, stream>>>(odeW1, w1t, 3200, 4096);
    transpose_bf16<<<dim3(100, 128), 256, 0, stream>>>(odeW2, w2t, 4096, 3200);
    // y0 setup
    se_kernel<<<128, 256, 0, stream>>>(z, decW, decb, SE);
    init_kernel<<<4096, 128, 0, stream>>>(SE, tmpl, dW1, db1, dW2, db2,
                                          aW1, ab1, aW2, ab2, yst, ybf, out);

    const float dt  = 8.0f / 191.0f;
    const float dt2 = 0.5f * dt;
    const float dt6 = dt / 6.0f;

    for (int s = 0; s < 191; ++s) {
        float* traj = out + (size_t)(s + 1) * 409600;
        // eval 1
        gemm_step<<<256, 256, 0, stream>>>(ybf, w1t, odeb1, 3200, 64, 0, 0.f, 0.f,
                                           hbf, nullptr, nullptr, nullptr);
        gemm_step<<<200, 256, 0, stream>>>(hbf, w2t, odeb2, 4096, 50, 1, dt2, dt6,
                                           ybf, yst, Sac, nullptr);
        // eval 2
        gemm_step<<<256, 256, 0, stream>>>(ybf, w1t, odeb1, 3200, 64, 0, 0.f, 0.f,
                                           hbf, nullptr, nullptr, nullptr);
        gemm_step<<<200, 256, 0, stream>>>(hbf, w2t, odeb2, 4096, 50, 2, dt2, dt6,
                                           ybf, yst, Sac, nullptr);
        // eval 3
        gemm_step<<<256, 256, 0, stream>>>(ybf, w1t, odeb1, 3200, 64, 0, 0.f, 0.f,
                                           hbf, nullptr, nullptr, nullptr);
        gemm_step<<<200, 256, 0, stream>>>(hbf, w2t, odeb2, 4096, 50, 2, dt, dt6,
                                           ybf, yst, Sac, nullptr);
        // eval 4 + RK4 combine + trajectory write
        gemm_step<<<256, 256, 0, stream>>>(ybf, w1t, odeb1, 3200, 64, 0, 0.f, 0.f,
                                           hbf, nullptr, nullptr, nullptr);
        gemm_step<<<200, 256, 0, stream>>>(hbf, w2t, odeb2, 4096, 50, 3, 0.f, dt6,
                                           ybf, yst, Sac, traj);
    }
}